// Round 9
// baseline (136.419 us; speedup 1.0000x reference)
//
#include <hip/hip_runtime.h>
#include <hip/hip_fp16.h>
#include <math.h>

static constexpr int N_NODES = 50000;
static constexpr int N_EDGES = 800000;
static constexpr int NFEAT = 512;
static constexpr int NHID = 96;
static constexpr int NCLASS = 40;
static constexpr int PREP_BLOCKS = 196;        // 196*256 = 50176 >= N_NODES
static constexpr int GEMM1_BLOCKS = (N_NODES + 63) / 64;   // 782
static constexpr int EDGE_BLOCKS = (N_EDGES + 255) / 256;  // 3125
static constexpr int BUCKET = 64;              // max degree capacity (P(deg>63)~1e-13)
static constexpr int W2LD = 104;               // padded row stride (bf16)

typedef __bf16 bf16_t;
typedef __attribute__((ext_vector_type(8))) __bf16 bf16x8;
typedef __attribute__((ext_vector_type(4))) float f32x4;

// ---------------------------------------------------------------------------
// Zero-fill (fallback path only)
// ---------------------------------------------------------------------------
__global__ __launch_bounds__(256) void k_zero(int* __restrict__ p, int n) {
    int i = blockIdx.x * 256 + threadIdx.x;
    if (i < n) p[i] = 0;
}

// ---------------------------------------------------------------------------
// Prep (fused): W1 -> w1t bf16 transposed; W2 -> w2t bf16 transposed+padded;
// zero cnt[50000] (bucket cursors / degree counts).
// ---------------------------------------------------------------------------
__global__ __launch_bounds__(256) void k_prep(const float* __restrict__ W1,
                                              const float* __restrict__ W2,
                                              bf16_t* __restrict__ w1t,
                                              bf16_t* __restrict__ w2t,
                                              int* __restrict__ cnt) {
    int e = blockIdx.x * 256 + threadIdx.x;
    if (e < N_NODES) cnt[e] = 0;
    if (e < NFEAT * NHID) {
        int k = e / NHID;
        int n = e - k * NHID;
        w1t[(size_t)n * NFEAT + k] = (bf16_t)W1[e];
    }
    if (e < 48 * NHID) {
        int n = e / NHID;
        int k = e - n * NHID;
        w2t[n * W2LD + k] = (n < NCLASS) ? (bf16_t)W2[k * NCLASS + n] : (bf16_t)0.f;
    }
}

// ---------------------------------------------------------------------------
// FUSED GEMM1 (bf16 MFMA, BARRIER-FREE) + padded-bucket scatter.
// GEMM path: NO LDS, NO __syncthreads. B-fragments load directly from
// w1t (96KB, L2-resident, reused by all 782 blocks). Rationale: hipcc drains
// vmcnt(0) before every s_barrier, so the old 2-barrier-per-K-tile staging
// loop serialized the HBM x-loads (VALUBusy 2.8%, 62us). Barrier-free lets
// the compiler pipeline all 16 K-steps' loads with counted vmcnt; LDS=0 also
// lifts occupancy for gemm AND co-scheduled scatter blocks.
// Scatter path: edge -> buck[dst*64+rank], record (src:u16<<16)|f16(w).
// ---------------------------------------------------------------------------
static __device__ inline bf16x8 cvt8(float4 u, float4 v) {
    bf16x8 r;
    r[0] = (bf16_t)u.x; r[1] = (bf16_t)u.y; r[2] = (bf16_t)u.z; r[3] = (bf16_t)u.w;
    r[4] = (bf16_t)v.x; r[5] = (bf16_t)v.y; r[6] = (bf16_t)v.z; r[7] = (bf16_t)v.w;
    return r;
}

__global__ __launch_bounds__(256) void k_gemm1_scatter(
        const float* __restrict__ x, const bf16_t* __restrict__ w1t,
        const float* __restrict__ b1, bf16_t* __restrict__ support,
        const int* __restrict__ src, const int* __restrict__ dst,
        const float* __restrict__ ew, int* __restrict__ cnt,
        unsigned int* __restrict__ buck) {
    const int tid = threadIdx.x;

    if (blockIdx.x >= GEMM1_BLOCKS) {  // scatter path (block-uniform branch)
        int i = (blockIdx.x - GEMM1_BLOCKS) * 256 + tid;
        if (i < N_EDGES) {
            int d = dst[i];
            int rank = atomicAdd(&cnt[d], 1);
            if (rank < BUCKET) {
                __half hh = __float2half(ew[i]);
                unsigned short us = *reinterpret_cast<unsigned short*>(&hh);
                buck[(size_t)d * BUCKET + rank] =
                    ((unsigned int)src[i] << 16) | (unsigned int)us;
            }
        }
        return;
    }

    const int w = tid >> 6;
    const int l = tid & 63;
    const int row0 = blockIdx.x * 64;
    const int kq = l >> 4;          // k-quad 0..3, 8 floats each

    int arow = row0 + w * 16 + (l & 15);
    if (arow > N_NODES - 1) arow = N_NODES - 1;  // clamp: dup loads, masked store
    const float* ap = x + (size_t)arow * NFEAT + (kq << 3);

    // B-fragment base pointers: lane l serves col n = nt*16 + (l&15)
    const bf16_t* bp[6];
#pragma unroll
    for (int nt = 0; nt < 6; ++nt)
        bp[nt] = w1t + (size_t)(nt * 16 + (l & 15)) * NFEAT + (kq << 3);

    f32x4 acc[6];
#pragma unroll
    for (int nt = 0; nt < 6; ++nt) acc[nt] = (f32x4){0.f, 0.f, 0.f, 0.f};

#pragma unroll 4
    for (int ks = 0; ks < 16; ++ks) {    // 16 K-steps of 32
        const int ko = ks * 32;
        float4 u = *reinterpret_cast<const float4*>(ap + ko);
        float4 v = *reinterpret_cast<const float4*>(ap + ko + 4);
        bf16x8 bf0 = *reinterpret_cast<const bf16x8*>(bp[0] + ko);
        bf16x8 bf1 = *reinterpret_cast<const bf16x8*>(bp[1] + ko);
        bf16x8 bf2 = *reinterpret_cast<const bf16x8*>(bp[2] + ko);
        bf16x8 bf3 = *reinterpret_cast<const bf16x8*>(bp[3] + ko);
        bf16x8 bf4 = *reinterpret_cast<const bf16x8*>(bp[4] + ko);
        bf16x8 bf5 = *reinterpret_cast<const bf16x8*>(bp[5] + ko);
        bf16x8 af = cvt8(u, v);
        acc[0] = __builtin_amdgcn_mfma_f32_16x16x32_bf16(af, bf0, acc[0], 0, 0, 0);
        acc[1] = __builtin_amdgcn_mfma_f32_16x16x32_bf16(af, bf1, acc[1], 0, 0, 0);
        acc[2] = __builtin_amdgcn_mfma_f32_16x16x32_bf16(af, bf2, acc[2], 0, 0, 0);
        acc[3] = __builtin_amdgcn_mfma_f32_16x16x32_bf16(af, bf3, acc[3], 0, 0, 0);
        acc[4] = __builtin_amdgcn_mfma_f32_16x16x32_bf16(af, bf4, acc[4], 0, 0, 0);
        acc[5] = __builtin_amdgcn_mfma_f32_16x16x32_bf16(af, bf5, acc[5], 0, 0, 0);
    }

    // Epilogue: C layout col=lane&15, row=(lane>>4)*4+reg (m89-verified)
    const int col16 = l & 15;
#pragma unroll
    for (int nt = 0; nt < 6; ++nt) {
        int col = nt * 16 + col16;
        float bv = b1[col];
#pragma unroll
        for (int r = 0; r < 4; ++r) {
            int row = row0 + w * 16 + kq * 4 + r;
            if (row < N_NODES)
                support[(size_t)row * NHID + col] = (bf16_t)(acc[nt][r] + bv);
        }
    }
}

// ---------------------------------------------------------------------------
// Pull-mode aggregate + ReLU from padded buckets.
// One 32-lane group per node; uint4 loads 4 packed edge records at once;
// 12 support-gathers in flight per unrolled iter.
// ---------------------------------------------------------------------------
static __device__ inline float dec_w(unsigned int v) {
    unsigned short us = (unsigned short)(v & 0xffffu);
    __half hh = *reinterpret_cast<__half*>(&us);
    return __half2float(hh);
}

__global__ __launch_bounds__(256) void k_agg(const bf16_t* __restrict__ support,
                                             const int* __restrict__ cnt,
                                             const unsigned int* __restrict__ buck,
                                             bf16_t* __restrict__ h) {
    const int g = blockIdx.x * 8 + (threadIdx.x >> 5);
    const int l = threadIdx.x & 31;
    if (g >= N_NODES) return;
    int deg = cnt[g];
    if (deg > BUCKET) deg = BUCKET;  // safety clamp (stat. unreachable)
    const unsigned int* bk = buck + (size_t)g * BUCKET;
    float a0 = 0.f, a1 = 0.f, a2 = 0.f;
    int e = 0;
    for (; e + 4 <= deg; e += 4) {
        uint4 q = *reinterpret_cast<const uint4*>(bk + e);
        const bf16_t* r0 = support + (size_t)(q.x >> 16) * NHID;
        const bf16_t* r1 = support + (size_t)(q.y >> 16) * NHID;
        const bf16_t* r2 = support + (size_t)(q.z >> 16) * NHID;
        const bf16_t* r3 = support + (size_t)(q.w >> 16) * NHID;
        float w0 = dec_w(q.x), w1 = dec_w(q.y), w2 = dec_w(q.z), w3 = dec_w(q.w);
        float v00 = (float)r0[l], v01 = (float)r0[l + 32], v02 = (float)r0[l + 64];
        float v10 = (float)r1[l], v11 = (float)r1[l + 32], v12 = (float)r1[l + 64];
        float v20 = (float)r2[l], v21 = (float)r2[l + 32], v22 = (float)r2[l + 64];
        float v30 = (float)r3[l], v31 = (float)r3[l + 32], v32 = (float)r3[l + 64];
        a0 = fmaf(w0, v00, a0); a1 = fmaf(w0, v01, a1); a2 = fmaf(w0, v02, a2);
        a0 = fmaf(w1, v10, a0); a1 = fmaf(w1, v11, a1); a2 = fmaf(w1, v12, a2);
        a0 = fmaf(w2, v20, a0); a1 = fmaf(w2, v21, a1); a2 = fmaf(w2, v22, a2);
        a0 = fmaf(w3, v30, a0); a1 = fmaf(w3, v31, a1); a2 = fmaf(w3, v32, a2);
    }
    for (; e < deg; ++e) {
        unsigned int v = bk[e];
        const bf16_t* r = support + (size_t)(v >> 16) * NHID;
        float wv = dec_w(v);
        a0 = fmaf(wv, (float)r[l], a0);
        a1 = fmaf(wv, (float)r[l + 32], a1);
        a2 = fmaf(wv, (float)r[l + 64], a2);
    }
    bf16_t* hr = h + (size_t)g * NHID;
    hr[l]      = (bf16_t)fmaxf(a0, 0.f);
    hr[l + 32] = (bf16_t)fmaxf(a1, 0.f);
    hr[l + 64] = (bf16_t)fmaxf(a2, 0.f);
}

// ---------------------------------------------------------------------------
// GEMM2 (bf16 MFMA) + bias + log_softmax fused (R4-proven).
// ---------------------------------------------------------------------------
__global__ __launch_bounds__(256) void k_gemm2_mfma(const bf16_t* __restrict__ h,
                                                    const bf16_t* __restrict__ w2t,
                                                    const float* __restrict__ b2,
                                                    float* __restrict__ out) {
    __shared__ bf16_t Bs[48 * W2LD];
    const int tid = threadIdx.x;
#pragma unroll
    for (int i = tid; i < 48 * W2LD / 8; i += 256)
        *reinterpret_cast<uint4*>(Bs + i * 8) =
            *reinterpret_cast<const uint4*>(w2t + i * 8);

    const int w = tid >> 6;
    const int l = tid & 63;
    const int row0 = blockIdx.x * 64 + w * 16;
    int arow = row0 + (l & 15);
    if (arow > N_NODES - 1) arow = N_NODES - 1;
    const bf16_t* ap = h + (size_t)arow * NHID + ((l >> 4) << 3);

    f32x4 acc[3];
#pragma unroll
    for (int nt = 0; nt < 3; ++nt) acc[nt] = (f32x4){0.f, 0.f, 0.f, 0.f};
    __syncthreads();

#pragma unroll
    for (int ks = 0; ks < 3; ++ks) {
        bf16x8 af = *reinterpret_cast<const bf16x8*>(ap + ks * 32);
#pragma unroll
        for (int nt = 0; nt < 3; ++nt) {
            int n = nt * 16 + (l & 15);
            bf16x8 bf = *reinterpret_cast<const bf16x8*>(
                &Bs[n * W2LD + ks * 32 + ((l >> 4) << 3)]);
            acc[nt] = __builtin_amdgcn_mfma_f32_16x16x32_bf16(af, bf, acc[nt], 0, 0, 0);
        }
    }

    const int c16 = l & 15;
    float bv[3];
    bool val[3];
#pragma unroll
    for (int nt = 0; nt < 3; ++nt) {
        int col = nt * 16 + c16;
        val[nt] = col < NCLASS;
        bv[nt] = val[nt] ? b2[col] : 0.f;
    }
#pragma unroll
    for (int r = 0; r < 4; ++r) {
        float lg[3];
        float m = -1e30f;
#pragma unroll
        for (int nt = 0; nt < 3; ++nt) {
            lg[nt] = acc[nt][r] + bv[nt];
            if (val[nt]) m = fmaxf(m, lg[nt]);
        }
#pragma unroll
        for (int off = 1; off < 16; off <<= 1) m = fmaxf(m, __shfl_xor(m, off));
        float s = 0.f;
#pragma unroll
        for (int nt = 0; nt < 3; ++nt)
            if (val[nt]) s += __expf(lg[nt] - m);
#pragma unroll
        for (int off = 1; off < 16; off <<= 1) s += __shfl_xor(s, off);
        float lse = __logf(s);
        int row = row0 + ((l >> 4) << 2) + r;
        if (row < N_NODES) {
#pragma unroll
            for (int nt = 0; nt < 3; ++nt)
                if (val[nt])
                    out[(size_t)row * NCLASS + nt * 16 + c16] = lg[nt] - m - lse;
        }
    }
}

// ---------------------------------------------------------------------------
// Fallback path (workspace too small for buckets)
// ---------------------------------------------------------------------------
__global__ __launch_bounds__(256) void k_agg_atomic(const bf16_t* __restrict__ support,
                                                    const int* __restrict__ src,
                                                    const int* __restrict__ dst,
                                                    const float* __restrict__ ew,
                                                    float* __restrict__ hf) {
    int e = blockIdx.x * 8 + (threadIdx.x >> 5);
    int l = threadIdx.x & 31;
    if (e >= N_EDGES) return;
    int s = src[e];
    int d = dst[e];
    float w = ew[e];
    const bf16_t* r = support + (size_t)s * NHID;
    float* hd = hf + (size_t)d * NHID;
    atomicAdd(&hd[l], w * (float)r[l]);
    atomicAdd(&hd[l + 32], w * (float)r[l + 32]);
    atomicAdd(&hd[l + 64], w * (float)r[l + 64]);
}

__global__ __launch_bounds__(256) void k_gemm2_fb(const float* __restrict__ hf,
                                                  const bf16_t* __restrict__ w2t,
                                                  const float* __restrict__ b2,
                                                  float* __restrict__ out) {
    __shared__ bf16_t hs[64][W2LD];
    __shared__ bf16_t Bs[48 * W2LD];
    const int tid = threadIdx.x;
#pragma unroll
    for (int i = tid; i < 48 * W2LD / 8; i += 256)
        *reinterpret_cast<uint4*>(Bs + i * 8) =
            *reinterpret_cast<const uint4*>(w2t + i * 8);
    const int row0 = blockIdx.x * 64;
    for (int i = tid; i < 64 * NHID; i += 256) {
        int r = i / NHID, c = i - r * NHID;
        int row = row0 + r;
        float v = (row < N_NODES) ? fmaxf(hf[(size_t)row * NHID + c], 0.f) : 0.f;
        hs[r][c] = (bf16_t)v;
    }
    __syncthreads();
    const int w = tid >> 6;
    const int l64 = tid & 63;
    const int r16 = l64 & 15;
    const int kq = l64 >> 4;
    f32x4 acc[3];
#pragma unroll
    for (int nt = 0; nt < 3; ++nt) acc[nt] = (f32x4){0.f, 0.f, 0.f, 0.f};
#pragma unroll
    for (int ks = 0; ks < 3; ++ks) {
        bf16x8 af = *reinterpret_cast<const bf16x8*>(&hs[w * 16 + r16][ks * 32 + (kq << 3)]);
#pragma unroll
        for (int nt = 0; nt < 3; ++nt) {
            int n = nt * 16 + r16;
            bf16x8 bf = *reinterpret_cast<const bf16x8*>(&Bs[n * W2LD + ks * 32 + (kq << 3)]);
            acc[nt] = __builtin_amdgcn_mfma_f32_16x16x32_bf16(af, bf, acc[nt], 0, 0, 0);
        }
    }
    float bv[3];
    bool val[3];
#pragma unroll
    for (int nt = 0; nt < 3; ++nt) {
        int col = nt * 16 + r16;
        val[nt] = col < NCLASS;
        bv[nt] = val[nt] ? b2[col] : 0.f;
    }
#pragma unroll
    for (int r = 0; r < 4; ++r) {
        float lg[3];
        float m = -1e30f;
#pragma unroll
        for (int nt = 0; nt < 3; ++nt) {
            lg[nt] = acc[nt][r] + bv[nt];
            if (val[nt]) m = fmaxf(m, lg[nt]);
        }
#pragma unroll
        for (int off = 1; off < 16; off <<= 1) m = fmaxf(m, __shfl_xor(m, off));
        float s = 0.f;
#pragma unroll
        for (int nt = 0; nt < 3; ++nt)
            if (val[nt]) s += __expf(lg[nt] - m);
#pragma unroll
        for (int off = 1; off < 16; off <<= 1) s += __shfl_xor(s, off);
        float lse = __logf(s);
        int row = row0 + w * 16 + kq * 4 + r;
        if (row < N_NODES) {
#pragma unroll
            for (int nt = 0; nt < 3; ++nt)
                if (val[nt])
                    out[(size_t)row * NCLASS + nt * 16 + r16] = lg[nt] - m - lse;
        }
    }
}

// ---------------------------------------------------------------------------
extern "C" void kernel_launch(void* const* d_in, const int* in_sizes, int n_in,
                              void* d_out, int out_size, void* d_ws, size_t ws_size,
                              hipStream_t stream) {
    const float* x  = (const float*)d_in[0];
    const int* ei   = (const int*)d_in[1];
    const float* ew = (const float*)d_in[2];
    const float* W1 = (const float*)d_in[3];
    const float* b1 = (const float*)d_in[4];
    const float* W2 = (const float*)d_in[5];
    const float* b2 = (const float*)d_in[6];
    float* out = (float*)d_out;
    const int* src = ei;
    const int* dst = ei + N_EDGES;

    char* ws = (char*)d_ws;
    size_t off = 0;
    auto alloc = [&](size_t bytes) -> void* {
        void* p = ws + off;
        off = (off + bytes + 255) & ~(size_t)255;
        return p;
    };
    bf16_t* support = (bf16_t*)alloc((size_t)N_NODES * NHID * 2);
    bf16_t* h       = (bf16_t*)alloc((size_t)N_NODES * NHID * 2);
    bf16_t* w1t     = (bf16_t*)alloc((size_t)NHID * NFEAT * 2);
    bf16_t* w2t     = (bf16_t*)alloc((size_t)48 * W2LD * 2);
    int* cnt        = (int*)alloc((size_t)N_NODES * 4);
    unsigned int* buck = (unsigned int*)alloc((size_t)N_NODES * BUCKET * 4);
    const bool fits = (off <= ws_size);
    float* hf       = (float*)alloc((size_t)N_NODES * NHID * 4);  // fallback only

    k_prep<<<PREP_BLOCKS, 256, 0, stream>>>(W1, W2, w1t, w2t, cnt);

    if (fits) {
        k_gemm1_scatter<<<GEMM1_BLOCKS + EDGE_BLOCKS, 256, 0, stream>>>(
            x, w1t, b1, support, src, dst, ew, cnt, buck);
        k_agg<<<(N_NODES + 7) / 8, 256, 0, stream>>>(support, cnt, buck, h);
        k_gemm2_mfma<<<GEMM1_BLOCKS, 256, 0, stream>>>(h, w2t, b2, out);
    } else {
        k_gemm1_scatter<<<GEMM1_BLOCKS, 256, 0, stream>>>(
            x, w1t, b1, support, src, dst, ew, cnt, buck);
        k_zero<<<(N_NODES * NHID + 255) / 256, 256, 0, stream>>>((int*)hf, N_NODES * NHID);
        k_agg_atomic<<<(N_EDGES + 7) / 8, 256, 0, stream>>>(support, src, dst, ew, hf);
        k_gemm2_fb<<<GEMM1_BLOCKS, 256, 0, stream>>>(hf, w2t, b2, out);
    }
}

// Round 10
// 103.120 us; speedup vs baseline: 1.3229x; 1.3229x over previous
//
#include <hip/hip_runtime.h>
#include <hip/hip_fp16.h>
#include <math.h>

static constexpr int N_NODES = 50000;
static constexpr int N_EDGES = 800000;
static constexpr int NFEAT = 512;
static constexpr int NHID = 96;
static constexpr int NCLASS = 40;
static constexpr int PREP_BLOCKS = 196;        // 196*256 = 50176 >= N_NODES
static constexpr int GEMM1_BLOCKS = (N_NODES + 63) / 64;   // 782
static constexpr int BUCKET = 64;              // max degree capacity (P(deg>63)~1e-13)
static constexpr int W2LD = 104;               // padded row stride (bf16)
// XCD-partitioned scatter geometry
static constexpr int SC_GROUPS = 8;            // one dst-range per XCD
static constexpr int SC_RANGE = N_NODES / SC_GROUPS;       // 6250
static constexpr int SC_CHUNK = 2048;          // edges scanned per block
static constexpr int SC_CHUNKS = (N_EDGES + SC_CHUNK - 1) / SC_CHUNK;  // 391
static constexpr int SCATTER_BLOCKS = SC_GROUPS * SC_CHUNKS;           // 3128

typedef __bf16 bf16_t;
typedef __attribute__((ext_vector_type(8))) __bf16 bf16x8;
typedef __attribute__((ext_vector_type(4))) float f32x4;

// ---------------------------------------------------------------------------
// Zero-fill (fallback path only)
// ---------------------------------------------------------------------------
__global__ __launch_bounds__(256) void k_zero(int* __restrict__ p, int n) {
    int i = blockIdx.x * 256 + threadIdx.x;
    if (i < n) p[i] = 0;
}

// ---------------------------------------------------------------------------
// Prep (fused): W1 -> w1t bf16 transposed; W2 -> w2t bf16 transposed+padded;
// zero cnt[50000] (bucket cursors / degree counts).
// ---------------------------------------------------------------------------
__global__ __launch_bounds__(256) void k_prep(const float* __restrict__ W1,
                                              const float* __restrict__ W2,
                                              bf16_t* __restrict__ w1t,
                                              bf16_t* __restrict__ w2t,
                                              int* __restrict__ cnt) {
    int e = blockIdx.x * 256 + threadIdx.x;
    if (e < N_NODES) cnt[e] = 0;
    if (e < NFEAT * NHID) {
        int k = e / NHID;
        int n = e - k * NHID;
        w1t[(size_t)n * NFEAT + k] = (bf16_t)W1[e];
    }
    if (e < 48 * NHID) {
        int n = e / NHID;
        int k = e - n * NHID;
        w2t[n * W2LD + k] = (n < NCLASS) ? (bf16_t)W2[k * NCLASS + n] : (bf16_t)0.f;
    }
}

// ---------------------------------------------------------------------------
// FUSED GEMM1 (bf16 MFMA, R8-proven LDS-staged body) + XCD-partitioned
// padded-bucket scatter.
// GEMM blocks [0, GEMM1_BLOCKS): support = x @ W1 + b1.
// Scatter blocks: si = bid - GEMM1_BLOCKS; group g = si&7 (all blocks of a
// group land on one XCD under round-robin placement since si≡g mod 8);
// group g owns dst range [g*6250,(g+1)*6250) -> every bucket line + cnt
// counter is written by ONE XCD's L2 (kills the 19x cross-XCD partial-line
// writeback amplification seen in R8: WRITE_SIZE 60MB for 3.2MB payload).
// Cost: 8x re-scan of dst[] = 25.6MB of L2/L3-resident sequential reads.
// ---------------------------------------------------------------------------
static __device__ inline bf16x8 cvt8(float4 u, float4 v) {
    bf16x8 r;
    r[0] = (bf16_t)u.x; r[1] = (bf16_t)u.y; r[2] = (bf16_t)u.z; r[3] = (bf16_t)u.w;
    r[4] = (bf16_t)v.x; r[5] = (bf16_t)v.y; r[6] = (bf16_t)v.z; r[7] = (bf16_t)v.w;
    return r;
}

__global__ __launch_bounds__(256) void k_gemm1_scatter(
        const float* __restrict__ x, const bf16_t* __restrict__ w1t,
        const float* __restrict__ b1, bf16_t* __restrict__ support,
        const int* __restrict__ src, const int* __restrict__ dst,
        const float* __restrict__ ew, int* __restrict__ cnt,
        unsigned int* __restrict__ buck) {
    __shared__ bf16_t Bs[NHID * 64];  // [n][k] 96x64 bf16 = 12KB, XOR-swizzled
    const int tid = threadIdx.x;

    if (blockIdx.x >= GEMM1_BLOCKS) {  // scatter path (block-uniform branch)
        const int si = blockIdx.x - GEMM1_BLOCKS;
        const int g = si & 7;           // dst-range group == XCD-coherent set
        const int c = si >> 3;          // edge chunk 0..SC_CHUNKS-1
        const int lo = g * SC_RANGE;
        const int hi = lo + SC_RANGE;
        const int base = c * SC_CHUNK;
#pragma unroll
        for (int t = 0; t < SC_CHUNK / 256; ++t) {
            int i = base + t * 256 + tid;
            if (i < N_EDGES) {
                int d = dst[i];
                if (d >= lo && d < hi) {
                    int rank = atomicAdd(&cnt[d], 1);
                    if (rank < BUCKET) {
                        __half hh = __float2half(ew[i]);
                        unsigned short us = *reinterpret_cast<unsigned short*>(&hh);
                        buck[(size_t)d * BUCKET + rank] =
                            ((unsigned int)src[i] << 16) | (unsigned int)us;
                    }
                }
            }
        }
        return;
    }

    const int w = tid >> 6;
    const int l = tid & 63;
    const int row0 = blockIdx.x * 64;

    int arow = row0 + w * 16 + (l & 15);
    if (arow > N_NODES - 1) arow = N_NODES - 1;  // clamp: dup loads, masked store
    const float* ap = x + (size_t)arow * NFEAT + ((l >> 4) << 3);

    f32x4 acc[6];
#pragma unroll
    for (int nt = 0; nt < 6; ++nt) acc[nt] = (f32x4){0.f, 0.f, 0.f, 0.f};

    for (int kt = 0; kt < NFEAT; kt += 64) {
        float4 a0 = *reinterpret_cast<const float4*>(ap + kt);
        float4 a1 = *reinterpret_cast<const float4*>(ap + kt + 4);
        float4 a2 = *reinterpret_cast<const float4*>(ap + kt + 32);
        float4 a3 = *reinterpret_cast<const float4*>(ap + kt + 36);

        __syncthreads();
#pragma unroll
        for (int p = 0; p < 3; ++p) {
            int idx = tid + p * 256;
            int n = idx >> 3;
            int c4 = idx & 7;
            uint4 v = *reinterpret_cast<const uint4*>(w1t + (size_t)n * NFEAT + kt + c4 * 8);
            int ba = (n * 128 + c4 * 16) ^ ((n & 7) << 4);
            *reinterpret_cast<uint4*>(reinterpret_cast<char*>(Bs) + ba) = v;
        }
        __syncthreads();

        bf16x8 af0 = cvt8(a0, a1);
        bf16x8 af1 = cvt8(a2, a3);
        const int koff = (l >> 4) << 4;
#pragma unroll
        for (int nt = 0; nt < 6; ++nt) {
            int n = nt * 16 + (l & 15);
            int ba0 = (n * 128 + koff) ^ ((n & 7) << 4);
            int ba1 = (n * 128 + 64 + koff) ^ ((n & 7) << 4);
            bf16x8 bf0 = *reinterpret_cast<const bf16x8*>(reinterpret_cast<const char*>(Bs) + ba0);
            bf16x8 bf1 = *reinterpret_cast<const bf16x8*>(reinterpret_cast<const char*>(Bs) + ba1);
            acc[nt] = __builtin_amdgcn_mfma_f32_16x16x32_bf16(af0, bf0, acc[nt], 0, 0, 0);
            acc[nt] = __builtin_amdgcn_mfma_f32_16x16x32_bf16(af1, bf1, acc[nt], 0, 0, 0);
        }
    }

    // Epilogue: C layout col=lane&15, row=(lane>>4)*4+reg (m89-verified)
    const int col16 = l & 15;
    const int rq = l >> 4;
#pragma unroll
    for (int nt = 0; nt < 6; ++nt) {
        int col = nt * 16 + col16;
        float bv = b1[col];
#pragma unroll
        for (int r = 0; r < 4; ++r) {
            int row = row0 + w * 16 + rq * 4 + r;
            if (row < N_NODES)
                support[(size_t)row * NHID + col] = (bf16_t)(acc[nt][r] + bv);
        }
    }
}

// ---------------------------------------------------------------------------
// Pull-mode aggregate + ReLU from padded buckets.
// One 32-lane group per node; uint4 loads 4 packed edge records at once;
// 12 support-gathers in flight per unrolled iter.
// ---------------------------------------------------------------------------
static __device__ inline float dec_w(unsigned int v) {
    unsigned short us = (unsigned short)(v & 0xffffu);
    __half hh = *reinterpret_cast<__half*>(&us);
    return __half2float(hh);
}

__global__ __launch_bounds__(256) void k_agg(const bf16_t* __restrict__ support,
                                             const int* __restrict__ cnt,
                                             const unsigned int* __restrict__ buck,
                                             bf16_t* __restrict__ h) {
    const int g = blockIdx.x * 8 + (threadIdx.x >> 5);
    const int l = threadIdx.x & 31;
    if (g >= N_NODES) return;
    int deg = cnt[g];
    if (deg > BUCKET) deg = BUCKET;  // safety clamp (stat. unreachable)
    const unsigned int* bk = buck + (size_t)g * BUCKET;
    float a0 = 0.f, a1 = 0.f, a2 = 0.f;
    int e = 0;
    for (; e + 4 <= deg; e += 4) {
        uint4 q = *reinterpret_cast<const uint4*>(bk + e);
        const bf16_t* r0 = support + (size_t)(q.x >> 16) * NHID;
        const bf16_t* r1 = support + (size_t)(q.y >> 16) * NHID;
        const bf16_t* r2 = support + (size_t)(q.z >> 16) * NHID;
        const bf16_t* r3 = support + (size_t)(q.w >> 16) * NHID;
        float w0 = dec_w(q.x), w1 = dec_w(q.y), w2 = dec_w(q.z), w3 = dec_w(q.w);
        float v00 = (float)r0[l], v01 = (float)r0[l + 32], v02 = (float)r0[l + 64];
        float v10 = (float)r1[l], v11 = (float)r1[l + 32], v12 = (float)r1[l + 64];
        float v20 = (float)r2[l], v21 = (float)r2[l + 32], v22 = (float)r2[l + 64];
        float v30 = (float)r3[l], v31 = (float)r3[l + 32], v32 = (float)r3[l + 64];
        a0 = fmaf(w0, v00, a0); a1 = fmaf(w0, v01, a1); a2 = fmaf(w0, v02, a2);
        a0 = fmaf(w1, v10, a0); a1 = fmaf(w1, v11, a1); a2 = fmaf(w1, v12, a2);
        a0 = fmaf(w2, v20, a0); a1 = fmaf(w2, v21, a1); a2 = fmaf(w2, v22, a2);
        a0 = fmaf(w3, v30, a0); a1 = fmaf(w3, v31, a1); a2 = fmaf(w3, v32, a2);
    }
    for (; e < deg; ++e) {
        unsigned int v = bk[e];
        const bf16_t* r = support + (size_t)(v >> 16) * NHID;
        float wv = dec_w(v);
        a0 = fmaf(wv, (float)r[l], a0);
        a1 = fmaf(wv, (float)r[l + 32], a1);
        a2 = fmaf(wv, (float)r[l + 64], a2);
    }
    bf16_t* hr = h + (size_t)g * NHID;
    hr[l]      = (bf16_t)fmaxf(a0, 0.f);
    hr[l + 32] = (bf16_t)fmaxf(a1, 0.f);
    hr[l + 64] = (bf16_t)fmaxf(a2, 0.f);
}

// ---------------------------------------------------------------------------
// GEMM2 (bf16 MFMA) + bias + log_softmax fused (R4-proven).
// ---------------------------------------------------------------------------
__global__ __launch_bounds__(256) void k_gemm2_mfma(const bf16_t* __restrict__ h,
                                                    const bf16_t* __restrict__ w2t,
                                                    const float* __restrict__ b2,
                                                    float* __restrict__ out) {
    __shared__ bf16_t Bs[48 * W2LD];
    const int tid = threadIdx.x;
#pragma unroll
    for (int i = tid; i < 48 * W2LD / 8; i += 256)
        *reinterpret_cast<uint4*>(Bs + i * 8) =
            *reinterpret_cast<const uint4*>(w2t + i * 8);

    const int w = tid >> 6;
    const int l = tid & 63;
    const int row0 = blockIdx.x * 64 + w * 16;
    int arow = row0 + (l & 15);
    if (arow > N_NODES - 1) arow = N_NODES - 1;
    const bf16_t* ap = h + (size_t)arow * NHID + ((l >> 4) << 3);

    f32x4 acc[3];
#pragma unroll
    for (int nt = 0; nt < 3; ++nt) acc[nt] = (f32x4){0.f, 0.f, 0.f, 0.f};
    __syncthreads();

#pragma unroll
    for (int ks = 0; ks < 3; ++ks) {
        bf16x8 af = *reinterpret_cast<const bf16x8*>(ap + ks * 32);
#pragma unroll
        for (int nt = 0; nt < 3; ++nt) {
            int n = nt * 16 + (l & 15);
            bf16x8 bf = *reinterpret_cast<const bf16x8*>(
                &Bs[n * W2LD + ks * 32 + ((l >> 4) << 3)]);
            acc[nt] = __builtin_amdgcn_mfma_f32_16x16x32_bf16(af, bf, acc[nt], 0, 0, 0);
        }
    }

    const int c16 = l & 15;
    float bv[3];
    bool val[3];
#pragma unroll
    for (int nt = 0; nt < 3; ++nt) {
        int col = nt * 16 + c16;
        val[nt] = col < NCLASS;
        bv[nt] = val[nt] ? b2[col] : 0.f;
    }
#pragma unroll
    for (int r = 0; r < 4; ++r) {
        float lg[3];
        float m = -1e30f;
#pragma unroll
        for (int nt = 0; nt < 3; ++nt) {
            lg[nt] = acc[nt][r] + bv[nt];
            if (val[nt]) m = fmaxf(m, lg[nt]);
        }
#pragma unroll
        for (int off = 1; off < 16; off <<= 1) m = fmaxf(m, __shfl_xor(m, off));
        float s = 0.f;
#pragma unroll
        for (int nt = 0; nt < 3; ++nt)
            if (val[nt]) s += __expf(lg[nt] - m);
#pragma unroll
        for (int off = 1; off < 16; off <<= 1) s += __shfl_xor(s, off);
        float lse = __logf(s);
        int row = row0 + ((l >> 4) << 2) + r;
        if (row < N_NODES) {
#pragma unroll
            for (int nt = 0; nt < 3; ++nt)
                if (val[nt])
                    out[(size_t)row * NCLASS + nt * 16 + c16] = lg[nt] - m - lse;
        }
    }
}

// ---------------------------------------------------------------------------
// Fallback path (workspace too small for buckets)
// ---------------------------------------------------------------------------
__global__ __launch_bounds__(256) void k_agg_atomic(const bf16_t* __restrict__ support,
                                                    const int* __restrict__ src,
                                                    const int* __restrict__ dst,
                                                    const float* __restrict__ ew,
                                                    float* __restrict__ hf) {
    int e = blockIdx.x * 8 + (threadIdx.x >> 5);
    int l = threadIdx.x & 31;
    if (e >= N_EDGES) return;
    int s = src[e];
    int d = dst[e];
    float w = ew[e];
    const bf16_t* r = support + (size_t)s * NHID;
    float* hd = hf + (size_t)d * NHID;
    atomicAdd(&hd[l], w * (float)r[l]);
    atomicAdd(&hd[l + 32], w * (float)r[l + 32]);
    atomicAdd(&hd[l + 64], w * (float)r[l + 64]);
}

__global__ __launch_bounds__(256) void k_gemm2_fb(const float* __restrict__ hf,
                                                  const bf16_t* __restrict__ w2t,
                                                  const float* __restrict__ b2,
                                                  float* __restrict__ out) {
    __shared__ bf16_t hs[64][W2LD];
    __shared__ bf16_t Bs[48 * W2LD];
    const int tid = threadIdx.x;
#pragma unroll
    for (int i = tid; i < 48 * W2LD / 8; i += 256)
        *reinterpret_cast<uint4*>(Bs + i * 8) =
            *reinterpret_cast<const uint4*>(w2t + i * 8);
    const int row0 = blockIdx.x * 64;
    for (int i = tid; i < 64 * NHID; i += 256) {
        int r = i / NHID, c = i - r * NHID;
        int row = row0 + r;
        float v = (row < N_NODES) ? fmaxf(hf[(size_t)row * NHID + c], 0.f) : 0.f;
        hs[r][c] = (bf16_t)v;
    }
    __syncthreads();
    const int w = tid >> 6;
    const int l64 = tid & 63;
    const int r16 = l64 & 15;
    const int kq = l64 >> 4;
    f32x4 acc[3];
#pragma unroll
    for (int nt = 0; nt < 3; ++nt) acc[nt] = (f32x4){0.f, 0.f, 0.f, 0.f};
#pragma unroll
    for (int ks = 0; ks < 3; ++ks) {
        bf16x8 af = *reinterpret_cast<const bf16x8*>(&hs[w * 16 + r16][ks * 32 + (kq << 3)]);
#pragma unroll
        for (int nt = 0; nt < 3; ++nt) {
            int n = nt * 16 + r16;
            bf16x8 bf = *reinterpret_cast<const bf16x8*>(&Bs[n * W2LD + ks * 32 + (kq << 3)]);
            acc[nt] = __builtin_amdgcn_mfma_f32_16x16x32_bf16(af, bf, acc[nt], 0, 0, 0);
        }
    }
    float bv[3];
    bool val[3];
#pragma unroll
    for (int nt = 0; nt < 3; ++nt) {
        int col = nt * 16 + r16;
        val[nt] = col < NCLASS;
        bv[nt] = val[nt] ? b2[col] : 0.f;
    }
#pragma unroll
    for (int r = 0; r < 4; ++r) {
        float lg[3];
        float m = -1e30f;
#pragma unroll
        for (int nt = 0; nt < 3; ++nt) {
            lg[nt] = acc[nt][r] + bv[nt];
            if (val[nt]) m = fmaxf(m, lg[nt]);
        }
#pragma unroll
        for (int off = 1; off < 16; off <<= 1) m = fmaxf(m, __shfl_xor(m, off));
        float s = 0.f;
#pragma unroll
        for (int nt = 0; nt < 3; ++nt)
            if (val[nt]) s += __expf(lg[nt] - m);
#pragma unroll
        for (int off = 1; off < 16; off <<= 1) s += __shfl_xor(s, off);
        float lse = __logf(s);
        int row = row0 + w * 16 + kq * 4 + r;
        if (row < N_NODES) {
#pragma unroll
            for (int nt = 0; nt < 3; ++nt)
                if (val[nt])
                    out[(size_t)row * NCLASS + nt * 16 + r16] = lg[nt] - m - lse;
        }
    }
}

// ---------------------------------------------------------------------------
extern "C" void kernel_launch(void* const* d_in, const int* in_sizes, int n_in,
                              void* d_out, int out_size, void* d_ws, size_t ws_size,
                              hipStream_t stream) {
    const float* x  = (const float*)d_in[0];
    const int* ei   = (const int*)d_in[1];
    const float* ew = (const float*)d_in[2];
    const float* W1 = (const float*)d_in[3];
    const float* b1 = (const float*)d_in[4];
    const float* W2 = (const float*)d_in[5];
    const float* b2 = (const float*)d_in[6];
    float* out = (float*)d_out;
    const int* src = ei;
    const int* dst = ei + N_EDGES;

    char* ws = (char*)d_ws;
    size_t off = 0;
    auto alloc = [&](size_t bytes) -> void* {
        void* p = ws + off;
        off = (off + bytes + 255) & ~(size_t)255;
        return p;
    };
    bf16_t* support = (bf16_t*)alloc((size_t)N_NODES * NHID * 2);
    bf16_t* h       = (bf16_t*)alloc((size_t)N_NODES * NHID * 2);
    bf16_t* w1t     = (bf16_t*)alloc((size_t)NHID * NFEAT * 2);
    bf16_t* w2t     = (bf16_t*)alloc((size_t)48 * W2LD * 2);
    int* cnt        = (int*)alloc((size_t)N_NODES * 4);
    unsigned int* buck = (unsigned int*)alloc((size_t)N_NODES * BUCKET * 4);
    const bool fits = (off <= ws_size);
    float* hf       = (float*)alloc((size_t)N_NODES * NHID * 4);  // fallback only

    k_prep<<<PREP_BLOCKS, 256, 0, stream>>>(W1, W2, w1t, w2t, cnt);

    if (fits) {
        k_gemm1_scatter<<<GEMM1_BLOCKS + SCATTER_BLOCKS, 256, 0, stream>>>(
            x, w1t, b1, support, src, dst, ew, cnt, buck);
        k_agg<<<(N_NODES + 7) / 8, 256, 0, stream>>>(support, cnt, buck, h);
        k_gemm2_mfma<<<GEMM1_BLOCKS, 256, 0, stream>>>(h, w2t, b2, out);
    } else {
        k_gemm1_scatter<<<GEMM1_BLOCKS, 256, 0, stream>>>(
            x, w1t, b1, support, src, dst, ew, cnt, buck);
        k_zero<<<(N_NODES * NHID + 255) / 256, 256, 0, stream>>>((int*)hf, N_NODES * NHID);
        k_agg_atomic<<<(N_EDGES + 7) / 8, 256, 0, stream>>>(support, src, dst, ew, hf);
        k_gemm2_fb<<<GEMM1_BLOCKS, 256, 0, stream>>>(hf, w2t, b2, out);
    }
}